// Round 7
// baseline (272.880 us; speedup 1.0000x reference)
//
#include <hip/hip_runtime.h>
#include <hip/hip_bf16.h>
#include <math.h>

// Problem constants (B=1)
#define T_SEQ 4096
#define C_DIM 1024
#define N_HEADS 16
#define HEAD_D 64

typedef __bf16 bf16x8 __attribute__((ext_vector_type(8)));
typedef float f32x4 __attribute__((ext_vector_type(4)));

__device__ __forceinline__ unsigned int pack_bf16x2(float lo, float hi) {
  unsigned short a = __builtin_bit_cast(unsigned short, __float2bfloat16(lo));
  unsigned short b = __builtin_bit_cast(unsigned short, __float2bfloat16(hi));
  return (unsigned int)a | ((unsigned int)b << 16);
}

// Async global->LDS, 16B per lane, wave-uniform LDS base + lane*16.
__device__ __forceinline__ void load_lds16(const void* g, void* l) {
  __builtin_amdgcn_global_load_lds(
      (const __attribute__((address_space(1))) unsigned int*)g,
      (__attribute__((address_space(3))) unsigned int*)l, 16, 0, 0);
}

// ---------------------------------------------------------------------------
// fp32 -> bf16 cast, 8 elements/thread
// ---------------------------------------------------------------------------
__global__ __launch_bounds__(256) void cast_f32_bf16(
    const float* __restrict__ in, unsigned int* __restrict__ out, int n8) {
  const int i = blockIdx.x * 256 + threadIdx.x;
  if (i < n8) {
    const float4 a = ((const float4*)in)[2 * i];
    const float4 b = ((const float4*)in)[2 * i + 1];
    uint4 r;
    r.x = pack_bf16x2(a.x, a.y);
    r.y = pack_bf16x2(a.z, a.w);
    r.z = pack_bf16x2(b.x, b.y);
    r.w = pack_bf16x2(b.z, b.w);
    ((uint4*)out)[i] = r;
  }
}

// ---------------------------------------------------------------------------
// W[K][N] fp32 -> WT[N][K] bf16 (transpose + cast), 64x64 LDS tiles
// ---------------------------------------------------------------------------
__global__ __launch_bounds__(256) void transpose_cast_bf16(
    const float* __restrict__ W, unsigned int* __restrict__ WT, int K, int N) {
  __shared__ float tile[64][65];
  const int n0 = blockIdx.x * 64, k0 = blockIdx.y * 64;
  const int tid = threadIdx.x;
#pragma unroll
  for (int i = 0; i < 16; i++) {
    const int idx = i * 256 + tid;
    const int r = idx >> 6, c = idx & 63;  // r: k, c: n
    tile[r][c] = W[(size_t)(k0 + r) * N + n0 + c];
  }
  __syncthreads();
#pragma unroll
  for (int i = 0; i < 8; i++) {
    const int idx = i * 256 + tid;
    const int rn = idx >> 5, p = idx & 31;  // rn: n-row, p: k-pair
    WT[((size_t)(n0 + rn) * K + k0) / 2 + p] =
        pack_bf16x2(tile[2 * p][rn], tile[2 * p + 1][rn]);
  }
}

// ---------------------------------------------------------------------------
// bf16 MFMA GEMM (m97 structure): C[M][N] f32 = A[M][K]bf16 * Bt[N][K]bf16^T
// ---------------------------------------------------------------------------
__global__ __launch_bounds__(256) void gemm_bt_bf16(
    const unsigned short* __restrict__ A,   // [M][K]
    const unsigned short* __restrict__ Bt,  // [N][K]
    float* __restrict__ C, int M, int N, int K) {
  __shared__ __align__(16) unsigned short As[128 * 32];
  __shared__ __align__(16) unsigned short Bs[128 * 32];
  const int tid = threadIdx.x;
  const int w = tid >> 6, lane = tid & 63;
  const int quad = lane >> 4, l16 = lane & 15;
  const int bm = blockIdx.y * 128, bn = blockIdx.x * 128;
  const int mw = (w & 1) * 64, nw = (w >> 1) * 64;

  f32x4 acc[4][4];
#pragma unroll
  for (int mt = 0; mt < 4; mt++)
#pragma unroll
    for (int nt = 0; nt < 4; nt++) acc[mt][nt] = (f32x4){0.f, 0.f, 0.f, 0.f};

  const int crow = lane >> 2;
  const int cq = lane & 3;
  const unsigned short* Ab = A + (size_t)bm * K;
  const unsigned short* Bb = Bt + (size_t)bn * K;

  for (int k0 = 0; k0 < K; k0 += 32) {
#pragma unroll
    for (int i = 0; i < 2; i++) {
      const int c = w + i * 4;
      const int row = c * 16 + crow;
      load_lds16(Ab + (size_t)row * K + k0 + cq * 8, As + c * 512);
      load_lds16(Bb + (size_t)row * K + k0 + cq * 8, Bs + c * 512);
    }
    __syncthreads();

    bf16x8 af[4], bf[4];
#pragma unroll
    for (int mt = 0; mt < 4; mt++)
      af[mt] = __builtin_bit_cast(
          bf16x8, *(const int4*)(As + (mw + mt * 16 + l16) * 32 + quad * 8));
#pragma unroll
    for (int nt = 0; nt < 4; nt++)
      bf[nt] = __builtin_bit_cast(
          bf16x8, *(const int4*)(Bs + (nw + nt * 16 + l16) * 32 + quad * 8));
#pragma unroll
    for (int mt = 0; mt < 4; mt++)
#pragma unroll
      for (int nt = 0; nt < 4; nt++)
        acc[mt][nt] = __builtin_amdgcn_mfma_f32_16x16x32_bf16(
            af[mt], bf[nt], acc[mt][nt], 0, 0, 0);
    __syncthreads();
  }

#pragma unroll
  for (int mt = 0; mt < 4; mt++)
#pragma unroll
    for (int nt = 0; nt < 4; nt++)
#pragma unroll
      for (int reg = 0; reg < 4; reg++)
        C[(size_t)(bm + mw + mt * 16 + quad * 4 + reg) * N + bn + nw +
          nt * 16 + l16] = acc[mt][nt][reg];
}

// ---------------------------------------------------------------------------
// RoPE + split to bf16: Qb[h][t][d] (PRE-SCALED by 0.125*log2(e) so that
// exp2(Q'.K) == exp(0.125*Q.K)), Kb[h][t][d], Vt[h][d][t] (transposed).
// ---------------------------------------------------------------------------
__global__ __launch_bounds__(256) void rope_split_bf16(
    const float* __restrict__ qkv, unsigned short* __restrict__ Qb,
    unsigned short* __restrict__ Kb, unsigned short* __restrict__ Vt) {
  const int tb = blockIdx.x * 64;
  const int h = blockIdx.y;
  const int tid = threadIdx.x;

  const int j = tid & 31;
  const int r0 = tid >> 5;  // 0..7
  const float inv = powf(10000.0f, -(2.0f * (float)j) / 64.0f);
  const float QSCALE = 0.125f * 1.44269504089f;  // 1/sqrt(D) * log2(e)
  unsigned int* Qu = (unsigned int*)Qb;
  unsigned int* Ku = (unsigned int*)Kb;
#pragma unroll
  for (int rr = 0; rr < 8; rr++) {
    const int t = tb + r0 + rr * 8;
    float s, c;
    sincosf((float)t * inv, &s, &c);
    const float* base = qkv + (size_t)t * (3 * C_DIM) + h * HEAD_D + 2 * j;
    const float2 q2 = *(const float2*)(base);
    const float2 k2 = *(const float2*)(base + C_DIM);
    const float qe = (q2.x * c - q2.y * s) * QSCALE;
    const float qo = (q2.y * c + q2.x * s) * QSCALE;
    const float ke = k2.x * c - k2.y * s;
    const float ko = k2.y * c + k2.x * s;
    const size_t ridx = ((size_t)h * T_SEQ + t) * 32 + j;
    Qu[ridx] = pack_bf16x2(qe, qo);
    Ku[ridx] = pack_bf16x2(ke, ko);
  }

  __shared__ float vs[64][65];
#pragma unroll
  for (int i = 0; i < 16; i++) {
    const int idx = i * 256 + tid;
    const int r = idx >> 6, d = idx & 63;
    vs[r][d] = qkv[(size_t)(tb + r) * (3 * C_DIM) + 2 * C_DIM + h * HEAD_D + d];
  }
  __syncthreads();
  unsigned int* Vu = (unsigned int*)Vt;
#pragma unroll
  for (int i = 0; i < 8; i++) {
    const int idx = i * 256 + tid;
    const int d = idx >> 5, sp = idx & 31;
    Vu[((size_t)(h * HEAD_D + d)) * (T_SEQ / 2) + (tb >> 1) + sp] =
        pack_bf16x2(vs[2 * sp][d], vs[2 * sp + 1][d]);
  }
}

// ---------------------------------------------------------------------------
// Flash attention v5: 2 q-subtiles per wave (block q-tile = 128). K and V are
// MFMA A-operands, loaded from LDS once per wave per tile and reused across
// both q-subtiles -> 1.8x fewer LDS reads per FLOP. K and V both
// double-buffered -> single barrier per iteration; staging of tile it+1
// overlaps the whole compute of tile it. Grid 512: rep=b>>8, h=b&15 (XCD L2
// locality: 2 heads/XCD), u=(b>>4)&15, qq = rep ? 31-u : u (CU-pair sum 31 =
// perfect balance). No online max (|s| bounded); per-lane lsum. LDS 51.2 KB.
// ---------------------------------------------------------------------------
__global__ __launch_bounds__(256) void attn_mfma(
    const unsigned short* __restrict__ Qb, const unsigned short* __restrict__ Kb,
    const unsigned short* __restrict__ Vt, unsigned short* __restrict__ O) {
  const int b = blockIdx.x;
  const int rep = b >> 8;
  const int jj = b & 255;
  const int h = jj & 15;
  const int u = jj >> 4;  // 0..15
  const int qq = rep ? (31 - u) : u;

  const int tid = threadIdx.x;
  const int w = tid >> 6;
  const int lane = tid & 63;
  const int quad = lane >> 4;
  const int l16 = lane & 15;
  const int qb = qq * 128;
  const int qw = qb + w * 32;  // wave's 32 q rows (2 subtiles of 16)

  // K,V double-buffered [2][64 rows][64 cols]; 16B chunks XOR-swizzled
  // within a row: LDS chunk (r,c) = global (r, c^(r&7)).
  __shared__ __align__(16) unsigned short Ks[2][64 * 64];
  __shared__ __align__(16) unsigned short Vs[2][64 * 64];
  __shared__ __align__(16) unsigned short plds[4][2][16][72];  // [wave][sub][q][s]

  const unsigned short* Kh = Kb + (size_t)h * T_SEQ * HEAD_D;
  const unsigned short* Vh = Vt + (size_t)h * HEAD_D * T_SEQ;

  // Q B-frags per subtile (persist): B[k=d][n=q]: q = l16, d = quad*8+j
  bf16x8 bq[2][2];
#pragma unroll
  for (int sub = 0; sub < 2; sub++) {
    const unsigned short* qrow =
        Qb + ((size_t)h * T_SEQ + qw + sub * 16 + l16) * HEAD_D + quad * 8;
#pragma unroll
    for (int ks = 0; ks < 2; ks++)
      bq[sub][ks] = __builtin_bit_cast(bf16x8, *(const int4*)(qrow + ks * 32));
  }

  f32x4 o[2][4];  // O^T acc: o[sub][dt][reg] = O[q=l16][d=dt*16+quad*4+reg]
#pragma unroll
  for (int sub = 0; sub < 2; sub++)
#pragma unroll
    for (int dt = 0; dt < 4; dt++) o[sub][dt] = (f32x4){0.f, 0.f, 0.f, 0.f};
  float lsum[2] = {0.f, 0.f};

  const int sr = tid >> 3;  // staging row 0..31 (+32 on second issue)
  const int sc = tid & 7;   // staging 16B chunk 0..7
  const int ntiles = qb / 64 + 2;

#define STAGE_K(buf, s0)                                                      \
  {                                                                           \
    _Pragma("unroll") for (int i = 0; i < 2; i++) {                           \
      const int r = sr + i * 32;                                              \
      const int cs = ((sc ^ (r & 7)) * 8);                                    \
      load_lds16(Kh + (size_t)((s0) + r) * HEAD_D + cs,                       \
                 &Ks[buf][(i * 4 + w) * 512]);                                \
    }                                                                         \
  }
#define STAGE_V(buf, s0)                                                      \
  {                                                                           \
    _Pragma("unroll") for (int i = 0; i < 2; i++) {                           \
      const int r = sr + i * 32;                                              \
      const int cs = ((sc ^ (r & 7)) * 8);                                    \
      load_lds16(Vh + (size_t)r * T_SEQ + (s0) + cs,                          \
                 &Vs[buf][(i * 4 + w) * 512]);                                \
    }                                                                         \
  }

  STAGE_K(0, 0);
  STAGE_V(0, 0);

  for (int it = 0; it < ntiles; it++) {
    const int s0 = it * 64;
    const int cur = it & 1;
    // single barrier: K[cur]/V[cur] staged (issued last iteration);
    // prev iteration's reads of buffer cur are complete.
    __syncthreads();
    if (it + 1 < ntiles) {
      STAGE_K(cur ^ 1, s0 + 64);
      STAGE_V(cur ^ 1, s0 + 64);
    }

    const unsigned short* Kt = Ks[cur];
    const unsigned short* Vtile = Vs[cur];

    // S^T = K Q^T for both q-subtiles; K A-frags loaded once, reused.
    // D-layout: key = nt*16 + quad*4 + reg, q = l16.
    f32x4 sv[2][4];
#pragma unroll
    for (int nt = 0; nt < 4; nt++) {
      const int key = nt * 16 + l16;
      const unsigned short* krow = Kt + key * 64;
      const bf16x8 a0 = __builtin_bit_cast(
          bf16x8, *(const int4*)(krow + ((quad ^ (key & 7)) * 8)));
      const bf16x8 a1 = __builtin_bit_cast(
          bf16x8, *(const int4*)(krow + (((4 + quad) ^ (key & 7)) * 8)));
#pragma unroll
      for (int sub = 0; sub < 2; sub++) {
        f32x4 z = (f32x4){0.f, 0.f, 0.f, 0.f};
        z = __builtin_amdgcn_mfma_f32_16x16x32_bf16(a0, bq[sub][0], z, 0, 0, 0);
        sv[sub][nt] =
            __builtin_amdgcn_mfma_f32_16x16x32_bf16(a1, bq[sub][1], z, 0, 0, 0);
      }
    }

    // per-sub: mask (tail tiles only), exp2, lsum, pack -> plds, bp frags
    bf16x8 bp[2][2];
#pragma unroll
    for (int sub = 0; sub < 2; sub++) {
      const int qg = qw + sub * 16 + l16;
      if (s0 + 63 > qg) {  // tile is (partially or fully) masked for this sub
#pragma unroll
        for (int nt = 0; nt < 4; nt++)
#pragma unroll
          for (int reg = 0; reg < 4; reg++) {
            const int sg = s0 + nt * 16 + quad * 4 + reg;
            if (sg > qg) sv[sub][nt][reg] = -1e30f;
          }
      }
#pragma unroll
      for (int nt = 0; nt < 4; nt++) {
        float p0 = exp2f(sv[sub][nt][0]), p1 = exp2f(sv[sub][nt][1]);
        float p2 = exp2f(sv[sub][nt][2]), p3 = exp2f(sv[sub][nt][3]);
        lsum[sub] += (p0 + p1) + (p2 + p3);
        uint2 pk;
        pk.x = pack_bf16x2(p0, p1);
        pk.y = pack_bf16x2(p2, p3);
        *(uint2*)&plds[w][sub][l16][nt * 16 + quad * 4] = pk;
      }
#pragma unroll
      for (int ks = 0; ks < 2; ks++)
        bp[sub][ks] = __builtin_bit_cast(
            bf16x8, *(const int4*)&plds[w][sub][l16][ks * 32 + quad * 8]);
    }

    // O^T += V^T P^T; V A-frags loaded once, reused for both subs.
#pragma unroll
    for (int dt = 0; dt < 4; dt++) {
      const int vrow = dt * 16 + l16;
      const unsigned short* vr = Vtile + vrow * 64;
      const bf16x8 a0 = __builtin_bit_cast(
          bf16x8, *(const int4*)(vr + ((quad ^ (vrow & 7)) * 8)));
      const bf16x8 a1 = __builtin_bit_cast(
          bf16x8, *(const int4*)(vr + (((4 + quad) ^ (vrow & 7)) * 8)));
#pragma unroll
      for (int sub = 0; sub < 2; sub++) {
        o[sub][dt] = __builtin_amdgcn_mfma_f32_16x16x32_bf16(a0, bp[sub][0],
                                                             o[sub][dt], 0, 0, 0);
        o[sub][dt] = __builtin_amdgcn_mfma_f32_16x16x32_bf16(a1, bp[sub][1],
                                                             o[sub][dt], 0, 0, 0);
      }
    }
  }
#undef STAGE_K
#undef STAGE_V

  // epilogue: reduce l across the 4 quads holding the same q = l16
#pragma unroll
  for (int sub = 0; sub < 2; sub++) {
    lsum[sub] += __shfl_xor(lsum[sub], 16, 64);
    lsum[sub] += __shfl_xor(lsum[sub], 32, 64);
    const float invl = 1.0f / lsum[sub];
    const int row = qw + sub * 16 + l16;
#pragma unroll
    for (int dt = 0; dt < 4; dt++) {
      uint2 pk;
      pk.x = pack_bf16x2(o[sub][dt][0] * invl, o[sub][dt][1] * invl);
      pk.y = pack_bf16x2(o[sub][dt][2] * invl, o[sub][dt][3] * invl);
      *(uint2*)(O + (size_t)row * C_DIM + h * HEAD_D + dt * 16 + quad * 4) = pk;
    }
  }
}

// ---------------------------------------------------------------------------
// Launch
// ---------------------------------------------------------------------------
extern "C" void kernel_launch(void* const* d_in, const int* in_sizes, int n_in,
                              void* d_out, int out_size, void* d_ws,
                              size_t ws_size, hipStream_t stream) {
  const float* x = (const float*)d_in[0];      // [T][C]
  const float* w_qkv = (const float*)d_in[1];  // [C][3C]
  const float* w_out = (const float*)d_in[2];  // [C][C]
  float* out = (float*)d_out;                  // [T][C]

  char* ws = (char*)d_ws;
  // Workspace layout (88 MB peak):
  //   [0, 48MB):  qkv fp32 [T][3C]; reused later as attn_ob bf16 [T][C]
  //   [48,56MB):  Qb bf16 [H][T][D] (pre-scaled by 0.125*log2e)
  //   [56,64MB):  Kb bf16 [H][T][D]
  //   [64,72MB):  Vt bf16 [H][D][T]
  //   [72,80MB):  xb bf16 [T][C]
  //   [80,86MB):  wqkvT bf16 [3C][C]
  //   [86,88MB):  woutT bf16 [C][C]
  float* qkv = (float*)ws;
  unsigned short* Qb = (unsigned short*)(ws + (size_t)48 * 1024 * 1024);
  unsigned short* Kb = (unsigned short*)(ws + (size_t)56 * 1024 * 1024);
  unsigned short* Vt = (unsigned short*)(ws + (size_t)64 * 1024 * 1024);
  unsigned short* xb = (unsigned short*)(ws + (size_t)72 * 1024 * 1024);
  unsigned short* wqkvT = (unsigned short*)(ws + (size_t)80 * 1024 * 1024);
  unsigned short* woutT = (unsigned short*)(ws + (size_t)86 * 1024 * 1024);
  unsigned short* attn_ob = (unsigned short*)ws;  // reuse qkv space

  dim3 blk(256);

  // 0) casts / transposes to bf16
  cast_f32_bf16<<<dim3((T_SEQ * C_DIM / 8) / 256), blk, 0, stream>>>(
      x, (unsigned int*)xb, T_SEQ * C_DIM / 8);
  transpose_cast_bf16<<<dim3(3 * C_DIM / 64, C_DIM / 64), blk, 0, stream>>>(
      w_qkv, (unsigned int*)wqkvT, C_DIM, 3 * C_DIM);
  transpose_cast_bf16<<<dim3(C_DIM / 64, C_DIM / 64), blk, 0, stream>>>(
      w_out, (unsigned int*)woutT, C_DIM, C_DIM);

  // 1) qkv = x @ w_qkv  (bf16 MFMA, fp32 out)
  gemm_bt_bf16<<<dim3(3 * C_DIM / 128, T_SEQ / 128), blk, 0, stream>>>(
      xb, wqkvT, qkv, T_SEQ, 3 * C_DIM, C_DIM);

  // 2) RoPE + bf16 split (+ V transpose)
  rope_split_bf16<<<dim3(T_SEQ / 64, N_HEADS), blk, 0, stream>>>(qkv, Qb, Kb,
                                                                 Vt);

  // 3) flash attention (2 q-subtiles/wave, K+V double-buffered, 1 barrier)
  attn_mfma<<<dim3(512), blk, 0, stream>>>(Qb, Kb, Vt, attn_ob);

  // 4) out = attn_o @ w_out (bf16 MFMA, fp32 out)
  gemm_bt_bf16<<<dim3(C_DIM / 128, T_SEQ / 128), blk, 0, stream>>>(
      attn_ob, woutT, out, T_SEQ, C_DIM, C_DIM);
}

// Round 8
// 228.343 us; speedup vs baseline: 1.1950x; 1.1950x over previous
//
#include <hip/hip_runtime.h>
#include <hip/hip_bf16.h>
#include <math.h>

// Problem constants (B=1)
#define T_SEQ 4096
#define C_DIM 1024
#define N_HEADS 16
#define HEAD_D 64

typedef __bf16 bf16x8 __attribute__((ext_vector_type(8)));
typedef float f32x4 __attribute__((ext_vector_type(4)));

__device__ __forceinline__ unsigned int pack_bf16x2(float lo, float hi) {
  unsigned short a = __builtin_bit_cast(unsigned short, __float2bfloat16(lo));
  unsigned short b = __builtin_bit_cast(unsigned short, __float2bfloat16(hi));
  return (unsigned int)a | ((unsigned int)b << 16);
}

// Async global->LDS, 16B per lane, wave-uniform LDS base + lane*16.
__device__ __forceinline__ void load_lds16(const void* g, void* l) {
  __builtin_amdgcn_global_load_lds(
      (const __attribute__((address_space(1))) unsigned int*)g,
      (__attribute__((address_space(3))) unsigned int*)l, 16, 0, 0);
}

// ---------------------------------------------------------------------------
// prep: x cast (blocks 0..2047) + w_qkv transpose (2048..2815) + w_out
// transpose (2816..3071). One launch instead of three.
// ---------------------------------------------------------------------------
__global__ __launch_bounds__(256) void prep_inputs(
    const float* __restrict__ x, const float* __restrict__ w_qkv,
    const float* __restrict__ w_out, unsigned int* __restrict__ xb,
    unsigned int* __restrict__ wqkvT, unsigned int* __restrict__ woutT) {
  __shared__ float tile[64][65];
  const int b = blockIdx.x;
  const int tid = threadIdx.x;

  if (b < 2048) {  // cast x -> bf16, 8 elems/thread
    const int i = b * 256 + tid;
    const float4 a = ((const float4*)x)[2 * i];
    const float4 c = ((const float4*)x)[2 * i + 1];
    uint4 r;
    r.x = pack_bf16x2(a.x, a.y);
    r.y = pack_bf16x2(a.z, a.w);
    r.z = pack_bf16x2(c.x, c.y);
    r.w = pack_bf16x2(c.z, c.w);
    ((uint4*)xb)[i] = r;
    return;
  }

  const float* W;
  unsigned int* WT;
  int N, bb;
  if (b < 2816) {
    W = w_qkv; WT = wqkvT; N = 3072; bb = b - 2048;
  } else {
    W = w_out; WT = woutT; N = 1024; bb = b - 2816;
  }
  const int K = 1024;
  const int n0 = (bb % (N / 64)) * 64, k0 = (bb / (N / 64)) * 64;
#pragma unroll
  for (int i = 0; i < 16; i++) {
    const int idx = i * 256 + tid;
    const int r = idx >> 6, c = idx & 63;  // r: k, c: n
    tile[r][c] = W[(size_t)(k0 + r) * N + n0 + c];
  }
  __syncthreads();
#pragma unroll
  for (int i = 0; i < 8; i++) {
    const int idx = i * 256 + tid;
    const int rn = idx >> 5, p = idx & 31;  // rn: n-row, p: k-pair
    WT[((size_t)(n0 + rn) * K + k0) / 2 + p] =
        pack_bf16x2(tile[2 * p][rn], tile[2 * p + 1][rn]);
  }
}

// ---------------------------------------------------------------------------
// bf16 MFMA GEMM (m97 structure): C[M][N] f32 = A[M][K]bf16 * Bt[N][K]bf16^T
// Tile 128x128, 4 waves 2x2. For large-N GEMMs (qkv projection).
// ---------------------------------------------------------------------------
__global__ __launch_bounds__(256) void gemm_bt_bf16(
    const unsigned short* __restrict__ A,   // [M][K]
    const unsigned short* __restrict__ Bt,  // [N][K]
    float* __restrict__ C, int M, int N, int K) {
  __shared__ __align__(16) unsigned short As[128 * 32];
  __shared__ __align__(16) unsigned short Bs[128 * 32];
  const int tid = threadIdx.x;
  const int w = tid >> 6, lane = tid & 63;
  const int quad = lane >> 4, l16 = lane & 15;
  const int bm = blockIdx.y * 128, bn = blockIdx.x * 128;
  const int mw = (w & 1) * 64, nw = (w >> 1) * 64;

  f32x4 acc[4][4];
#pragma unroll
  for (int mt = 0; mt < 4; mt++)
#pragma unroll
    for (int nt = 0; nt < 4; nt++) acc[mt][nt] = (f32x4){0.f, 0.f, 0.f, 0.f};

  const int crow = lane >> 2;
  const int cq = lane & 3;
  const unsigned short* Ab = A + (size_t)bm * K;
  const unsigned short* Bb = Bt + (size_t)bn * K;

  for (int k0 = 0; k0 < K; k0 += 32) {
#pragma unroll
    for (int i = 0; i < 2; i++) {
      const int c = w + i * 4;
      const int row = c * 16 + crow;
      load_lds16(Ab + (size_t)row * K + k0 + cq * 8, As + c * 512);
      load_lds16(Bb + (size_t)row * K + k0 + cq * 8, Bs + c * 512);
    }
    __syncthreads();

    bf16x8 af[4], bf[4];
#pragma unroll
    for (int mt = 0; mt < 4; mt++)
      af[mt] = __builtin_bit_cast(
          bf16x8, *(const int4*)(As + (mw + mt * 16 + l16) * 32 + quad * 8));
#pragma unroll
    for (int nt = 0; nt < 4; nt++)
      bf[nt] = __builtin_bit_cast(
          bf16x8, *(const int4*)(Bs + (nw + nt * 16 + l16) * 32 + quad * 8));
#pragma unroll
    for (int mt = 0; mt < 4; mt++)
#pragma unroll
      for (int nt = 0; nt < 4; nt++)
        acc[mt][nt] = __builtin_amdgcn_mfma_f32_16x16x32_bf16(
            af[mt], bf[nt], acc[mt][nt], 0, 0, 0);
    __syncthreads();
  }

#pragma unroll
  for (int mt = 0; mt < 4; mt++)
#pragma unroll
    for (int nt = 0; nt < 4; nt++)
#pragma unroll
      for (int reg = 0; reg < 4; reg++)
        C[(size_t)(bm + mw + mt * 16 + quad * 4 + reg) * N + bn + nw +
          nt * 16 + l16] = acc[mt][nt][reg];
}

// ---------------------------------------------------------------------------
// 64x64-tile variant for the out-projection (N=1024): grid (16,64) = 1024
// blocks -> 4 blocks/CU (the 128-tile gave only 256 blocks = 1/CU).
// 4 waves 2x2, each 32x32 per k-step. fp32 out.
// ---------------------------------------------------------------------------
__global__ __launch_bounds__(256) void gemm_bt_bf16_64(
    const unsigned short* __restrict__ A,   // [M][K]
    const unsigned short* __restrict__ Bt,  // [N][K]
    float* __restrict__ C, int M, int N, int K) {
  __shared__ __align__(16) unsigned short As[64 * 32];
  __shared__ __align__(16) unsigned short Bs[64 * 32];
  const int tid = threadIdx.x;
  const int w = tid >> 6, lane = tid & 63;
  const int quad = lane >> 4, l16 = lane & 15;
  const int bm = blockIdx.y * 64, bn = blockIdx.x * 64;
  const int mw = (w & 1) * 32, nw = (w >> 1) * 32;

  f32x4 acc[2][2];
#pragma unroll
  for (int mt = 0; mt < 2; mt++)
#pragma unroll
    for (int nt = 0; nt < 2; nt++) acc[mt][nt] = (f32x4){0.f, 0.f, 0.f, 0.f};

  const unsigned short* Ab = A + (size_t)bm * K;
  const unsigned short* Bb = Bt + (size_t)bn * K;
  const int srow = w * 16 + (lane >> 2);  // staging row for this lane
  const int scol = (lane & 3) * 8;        // 16B chunk within 64B row

  for (int k0 = 0; k0 < K; k0 += 32) {
    load_lds16(Ab + (size_t)srow * K + k0 + scol, As + w * 512);
    load_lds16(Bb + (size_t)srow * K + k0 + scol, Bs + w * 512);
    __syncthreads();

    bf16x8 af[2], bf[2];
#pragma unroll
    for (int mt = 0; mt < 2; mt++)
      af[mt] = __builtin_bit_cast(
          bf16x8, *(const int4*)(As + (mw + mt * 16 + l16) * 32 + quad * 8));
#pragma unroll
    for (int nt = 0; nt < 2; nt++)
      bf[nt] = __builtin_bit_cast(
          bf16x8, *(const int4*)(Bs + (nw + nt * 16 + l16) * 32 + quad * 8));
#pragma unroll
    for (int mt = 0; mt < 2; mt++)
#pragma unroll
      for (int nt = 0; nt < 2; nt++)
        acc[mt][nt] = __builtin_amdgcn_mfma_f32_16x16x32_bf16(
            af[mt], bf[nt], acc[mt][nt], 0, 0, 0);
    __syncthreads();
  }

#pragma unroll
  for (int mt = 0; mt < 2; mt++)
#pragma unroll
    for (int nt = 0; nt < 2; nt++)
#pragma unroll
      for (int reg = 0; reg < 4; reg++)
        C[(size_t)(bm + mw + mt * 16 + quad * 4 + reg) * N + bn + nw +
          nt * 16 + l16] = acc[mt][nt][reg];
}

// ---------------------------------------------------------------------------
// RoPE + split to bf16: Qb[h][t][d] (PRE-SCALED by 0.125*log2(e) so that
// exp2(Q'.K) == exp(0.125*Q.K)), Kb[h][t][d], Vt[h][d][t] (transposed).
// ---------------------------------------------------------------------------
__global__ __launch_bounds__(256) void rope_split_bf16(
    const float* __restrict__ qkv, unsigned short* __restrict__ Qb,
    unsigned short* __restrict__ Kb, unsigned short* __restrict__ Vt) {
  const int tb = blockIdx.x * 64;
  const int h = blockIdx.y;
  const int tid = threadIdx.x;

  const int j = tid & 31;
  const int r0 = tid >> 5;  // 0..7
  const float inv = powf(10000.0f, -(2.0f * (float)j) / 64.0f);
  const float QSCALE = 0.125f * 1.44269504089f;  // 1/sqrt(D) * log2(e)
  unsigned int* Qu = (unsigned int*)Qb;
  unsigned int* Ku = (unsigned int*)Kb;
#pragma unroll
  for (int rr = 0; rr < 8; rr++) {
    const int t = tb + r0 + rr * 8;
    float s, c;
    sincosf((float)t * inv, &s, &c);
    const float* base = qkv + (size_t)t * (3 * C_DIM) + h * HEAD_D + 2 * j;
    const float2 q2 = *(const float2*)(base);
    const float2 k2 = *(const float2*)(base + C_DIM);
    const float qe = (q2.x * c - q2.y * s) * QSCALE;
    const float qo = (q2.y * c + q2.x * s) * QSCALE;
    const float ke = k2.x * c - k2.y * s;
    const float ko = k2.y * c + k2.x * s;
    const size_t ridx = ((size_t)h * T_SEQ + t) * 32 + j;
    Qu[ridx] = pack_bf16x2(qe, qo);
    Ku[ridx] = pack_bf16x2(ke, ko);
  }

  __shared__ float vs[64][65];
#pragma unroll
  for (int i = 0; i < 16; i++) {
    const int idx = i * 256 + tid;
    const int r = idx >> 6, d = idx & 63;
    vs[r][d] = qkv[(size_t)(tb + r) * (3 * C_DIM) + 2 * C_DIM + h * HEAD_D + d];
  }
  __syncthreads();
  unsigned int* Vu = (unsigned int*)Vt;
#pragma unroll
  for (int i = 0; i < 8; i++) {
    const int idx = i * 256 + tid;
    const int d = idx >> 5, sp = idx & 31;
    Vu[((size_t)(h * HEAD_D + d)) * (T_SEQ / 2) + (tb >> 1) + sp] =
        pack_bf16x2(vs[2 * sp][d], vs[2 * sp + 1][d]);
  }
}

// ---------------------------------------------------------------------------
// Flash attention v4b (R6 structure + lsum-via-MFMA): operand-swapped MFMA
// (A=K, B=Q -> S^T; A=V^T, B=P^T -> O^T). Load-balance: CU sets {b, b+256,
// b+512, b+768} get qt = {u, 63-u, 16+u, 47-u} (sum 126). K double-buffered,
// V single-buffered (2-phase barrier). LDS 33792 B -> 4 blocks/CU. lsum is
// accumulated by an extra all-ones-A MFMA (idle pipe) instead of VALU adds;
// result is replicated across quads so the epilogue needs no shuffles.
// ---------------------------------------------------------------------------
__global__ __launch_bounds__(256) void attn_mfma(
    const unsigned short* __restrict__ Qb, const unsigned short* __restrict__ Kb,
    const unsigned short* __restrict__ Vt, unsigned short* __restrict__ O) {
  const int b = blockIdx.x;
  const int rep = b >> 8;
  const int jj = b & 255;
  const int h = jj & 15;
  const int u = jj >> 4;
  const int qmap[4] = {u, 63 - u, 16 + u, 47 - u};
  const int qt = qmap[rep];

  const int tid = threadIdx.x;
  const int w = tid >> 6;
  const int lane = tid & 63;
  const int quad = lane >> 4;
  const int l16 = lane & 15;
  const int qb = qt * 64;
  const int qw = qb + w * 16;

  // K: double-buffered [2][64 keys][64 dims]; V: single [64 dims][64 keys].
  // 16B chunks XOR-swizzled within a row: LDS chunk (r,c) = global (r, c^(r&7)).
  __shared__ __align__(16) unsigned short Ks[2][64 * 64];
  __shared__ __align__(16) unsigned short Vs[64 * 64];
  __shared__ __align__(16) unsigned short plds[4][16][72];  // [wave][q][s]

  const unsigned short* Kh = Kb + (size_t)h * T_SEQ * HEAD_D;
  const unsigned short* Vh = Vt + (size_t)h * HEAD_D * T_SEQ;

  // Q B-frags (persist): B[k=d][n=q]: q = l16, d = quad*8+j (+32 for ks=1)
  bf16x8 bq[2];
  {
    const unsigned short* qrow =
        Qb + ((size_t)h * T_SEQ + qw + l16) * HEAD_D + quad * 8;
#pragma unroll
    for (int ks = 0; ks < 2; ks++)
      bq[ks] = __builtin_bit_cast(bf16x8, *(const int4*)(qrow + ks * 32));
  }

  // all-ones A fragment for the lsum MFMA
  bf16x8 aones;
#pragma unroll
  for (int i = 0; i < 8; i++) aones[i] = (__bf16)1.0f;

  f32x4 o[4];  // O^T accumulator: o[dt][reg] = O[q=l16][d=dt*16+quad*4+reg]
#pragma unroll
  for (int dt = 0; dt < 4; dt++) o[dt] = (f32x4){0.f, 0.f, 0.f, 0.f};
  f32x4 lacc = (f32x4){0.f, 0.f, 0.f, 0.f};  // lsum via MFMA (col q=l16)

  const int sr = tid >> 3;  // staging row 0..31 (+32 on second issue)
  const int sc = tid & 7;   // staging 16B chunk 0..7
  const int ntiles = qb / 64 + 1;

#define STAGE_K(buf, s0)                                                      \
  {                                                                           \
    _Pragma("unroll") for (int i = 0; i < 2; i++) {                           \
      const int r = sr + i * 32;                                              \
      const int cs = ((sc ^ (r & 7)) * 8);                                    \
      load_lds16(Kh + (size_t)((s0) + r) * HEAD_D + cs,                       \
                 &Ks[buf][(i * 4 + w) * 512]);                                \
    }                                                                         \
  }
#define STAGE_V(s0)                                                           \
  {                                                                           \
    _Pragma("unroll") for (int i = 0; i < 2; i++) {                           \
      const int r = sr + i * 32;                                              \
      const int cs = ((sc ^ (r & 7)) * 8);                                    \
      load_lds16(Vh + (size_t)r * T_SEQ + (s0) + cs,                          \
                 &Vs[(i * 4 + w) * 512]);                                     \
    }                                                                         \
  }

  STAGE_K(0, 0);

  for (int it = 0; it < ntiles; it++) {
    const int s0 = it * 64;
    const int cur = it & 1;
    // barrier1: K[cur] staged; prev iteration's V reads complete
    __syncthreads();
    if (it + 1 < ntiles) STAGE_K(cur ^ 1, s0 + 64);
    STAGE_V(s0);

    const unsigned short* Kt = Ks[cur];

    // S^T = K Q^T  (Q pre-scaled by 0.125*log2e).
    // D-layout: key = nt*16 + quad*4 + reg, q = l16.
    f32x4 sv[4];
#pragma unroll
    for (int nt = 0; nt < 4; nt++) {
      const int key = nt * 16 + l16;
      const unsigned short* krow = Kt + key * 64;
      const bf16x8 a0 = __builtin_bit_cast(
          bf16x8, *(const int4*)(krow + ((quad ^ (key & 7)) * 8)));
      const bf16x8 a1 = __builtin_bit_cast(
          bf16x8, *(const int4*)(krow + (((4 + quad) ^ (key & 7)) * 8)));
      f32x4 z = (f32x4){0.f, 0.f, 0.f, 0.f};
      z = __builtin_amdgcn_mfma_f32_16x16x32_bf16(a0, bq[0], z, 0, 0, 0);
      sv[nt] = __builtin_amdgcn_mfma_f32_16x16x32_bf16(a1, bq[1], z, 0, 0, 0);
    }

    // causal mask: only the diagonal tile is partial
    if (s0 == qb) {
      const int qg = qw + l16;
#pragma unroll
      for (int nt = 0; nt < 4; nt++)
#pragma unroll
        for (int reg = 0; reg < 4; reg++) {
          const int sg = s0 + nt * 16 + quad * 4 + reg;
          if (sg > qg) sv[nt][reg] = -1e30f;
        }
    }

    // p = 2^s, pack 4 consecutive keys -> b64 LDS write (P^T layout [q][s])
#pragma unroll
    for (int nt = 0; nt < 4; nt++) {
      float p0 = exp2f(sv[nt][0]), p1 = exp2f(sv[nt][1]);
      float p2 = exp2f(sv[nt][2]), p3 = exp2f(sv[nt][3]);
      uint2 pk;
      pk.x = pack_bf16x2(p0, p1);
      pk.y = pack_bf16x2(p2, p3);
      *(uint2*)&plds[w][l16][nt * 16 + quad * 4] = pk;
    }

    // B-frags for PV: B[k=s][n=q]: q = l16, s = quad*8+j (+32)
    bf16x8 bp[2];
#pragma unroll
    for (int ks = 0; ks < 2; ks++)
      bp[ks] = __builtin_bit_cast(
          bf16x8, *(const int4*)&plds[w][l16][ks * 32 + quad * 8]);

    // lsum via MFMA: A = ones -> D[m][q] = sum_k P^T[k][q], all m identical
    lacc = __builtin_amdgcn_mfma_f32_16x16x32_bf16(aones, bp[0], lacc, 0, 0, 0);
    lacc = __builtin_amdgcn_mfma_f32_16x16x32_bf16(aones, bp[1], lacc, 0, 0, 0);

    // barrier2: V[cur] staged (QK+exp compute hid its latency)
    __syncthreads();

    // O^T += V^T P^T : A = V^T (m=d, k=s), B = P^T
#pragma unroll
    for (int dt = 0; dt < 4; dt++) {
      const int vrow = dt * 16 + l16;
      const unsigned short* vr = Vs + vrow * 64;
      const bf16x8 a0 = __builtin_bit_cast(
          bf16x8, *(const int4*)(vr + ((quad ^ (vrow & 7)) * 8)));
      const bf16x8 a1 = __builtin_bit_cast(
          bf16x8, *(const int4*)(vr + (((4 + quad) ^ (vrow & 7)) * 8)));
      o[dt] = __builtin_amdgcn_mfma_f32_16x16x32_bf16(a0, bp[0], o[dt], 0, 0, 0);
      o[dt] = __builtin_amdgcn_mfma_f32_16x16x32_bf16(a1, bp[1], o[dt], 0, 0, 0);
    }
  }
#undef STAGE_K
#undef STAGE_V

  // epilogue: lacc already holds the full sum over keys for q = l16
  // (replicated across regs/quads) -> no cross-lane reduction needed.
  const float invl = 1.0f / lacc[0];

  // O^T lane layout: q = l16, d = dt*16 + quad*4 + reg -> packed 8B stores
  const int row = qw + l16;
#pragma unroll
  for (int dt = 0; dt < 4; dt++) {
    uint2 pk;
    pk.x = pack_bf16x2(o[dt][0] * invl, o[dt][1] * invl);
    pk.y = pack_bf16x2(o[dt][2] * invl, o[dt][3] * invl);
    *(uint2*)(O + (size_t)row * C_DIM + h * HEAD_D + dt * 16 + quad * 4) = pk;
  }
}

// ---------------------------------------------------------------------------
// Launch
// ---------------------------------------------------------------------------
extern "C" void kernel_launch(void* const* d_in, const int* in_sizes, int n_in,
                              void* d_out, int out_size, void* d_ws,
                              size_t ws_size, hipStream_t stream) {
  const float* x = (const float*)d_in[0];      // [T][C]
  const float* w_qkv = (const float*)d_in[1];  // [C][3C]
  const float* w_out = (const float*)d_in[2];  // [C][C]
  float* out = (float*)d_out;                  // [T][C]

  char* ws = (char*)d_ws;
  // Workspace layout (88 MB peak):
  //   [0, 48MB):  qkv fp32 [T][3C]; reused later as attn_ob bf16 [T][C]
  //   [48,56MB):  Qb bf16 [H][T][D] (pre-scaled by 0.125*log2e)
  //   [56,64MB):  Kb bf16 [H][T][D]
  //   [64,72MB):  Vt bf16 [H][D][T]
  //   [72,80MB):  xb bf16 [T][C]
  //   [80,86MB):  wqkvT bf16 [3C][C]
  //   [86,88MB):  woutT bf16 [C][C]
  float* qkv = (float*)ws;
  unsigned short* Qb = (unsigned short*)(ws + (size_t)48 * 1024 * 1024);
  unsigned short* Kb = (unsigned short*)(ws + (size_t)56 * 1024 * 1024);
  unsigned short* Vt = (unsigned short*)(ws + (size_t)64 * 1024 * 1024);
  unsigned short* xb = (unsigned short*)(ws + (size_t)72 * 1024 * 1024);
  unsigned short* wqkvT = (unsigned short*)(ws + (size_t)80 * 1024 * 1024);
  unsigned short* woutT = (unsigned short*)(ws + (size_t)86 * 1024 * 1024);
  unsigned short* attn_ob = (unsigned short*)ws;  // reuse qkv space

  dim3 blk(256);

  // 0) fused cast + transposes (one launch)
  prep_inputs<<<dim3(3072), blk, 0, stream>>>(
      x, w_qkv, w_out, (unsigned int*)xb, (unsigned int*)wqkvT,
      (unsigned int*)woutT);

  // 1) qkv = x @ w_qkv  (bf16 MFMA, fp32 out), 768 blocks = 3/CU
  gemm_bt_bf16<<<dim3(3 * C_DIM / 128, T_SEQ / 128), blk, 0, stream>>>(
      xb, wqkvT, qkv, T_SEQ, 3 * C_DIM, C_DIM);

  // 2) RoPE + bf16 split (+ V transpose)
  rope_split_bf16<<<dim3(T_SEQ / 64, N_HEADS), blk, 0, stream>>>(qkv, Qb, Kb,
                                                                 Vt);

  // 3) flash attention (R6 structure + lsum-via-MFMA), 1024 blocks = 4/CU
  attn_mfma<<<dim3(1024), blk, 0, stream>>>(Qb, Kb, Vt, attn_ob);

  // 4) out = attn_o @ w_out (64x64 tiles, 1024 blocks = 4/CU)
  gemm_bt_bf16_64<<<dim3(C_DIM / 64, T_SEQ / 64), blk, 0, stream>>>(
      attn_ob, woutT, out, T_SEQ, C_DIM, C_DIM);
}